// Round 2
// baseline (1984.105 us; speedup 1.0000x reference)
//
#include <hip/hip_runtime.h>
#include <cstdint>
#include <cstddef>

// ---------------------------------------------------------------------------
// LatentActionGen forward on MI355X — fp32 baseline (round 1, resubmitted
// unchanged after GPU acquisition timeout; audited for correctness offline)
//
// Pipeline (all on `stream`, graph-capture safe):
//   memset(zero atomics) -> prep_weights -> stem -> 6x{convA, convB}
//   -> conv_out -> fc -> fcstats -> vq -> perplexity
//
// Activations kept NHWC ([b][p][c], p=h*6+w) for coalesced float4 access.
// Conv weights pre-transformed to [tap][ci/4][co][ci%4] (float4 per co).
// BatchNorm (training mode) fused: conv kernels accumulate per-channel
// sum/sumsq; consumer kernels apply BN(+add+relu) during load-to-LDS.
// fc bias cancels under bn_o mean subtraction -> skipped.
// ---------------------------------------------------------------------------

#define EPS_  1e-5f
#define NTOT_ 18432.0f   // B*H*W for conv BN stats

// workspace offsets (floats)
#define WSLOT(s)  ((size_t)(s) * 147456u)
#define BUFA_OFF  2138112u
#define BUFB_OFF  4497408u
#define BUFC_OFF  6856704u
#define FLAT_OFF  9216000u
#define FCO_OFF   10395648u
#define STATS_OFF 10461184u
// total = 10464512 floats = 41.9 MB

// d_out offsets (floats)
#define LOSS_OFF 2359296u
#define PERP_OFF 2359808u
#define IDX_OFF  2359809u

// ---------------------------------------------------------------------------
// Weight transform: src [O][I][3][3]  ->  wt[tap][ci/4][co][ci%4]
// ---------------------------------------------------------------------------
__global__ __launch_bounds__(256) void prep_weights(
    const float* __restrict__ conv_w, const float* __restrict__ convs_w,
    const float* __restrict__ c1w, const float* __restrict__ c2w,
    const float* __restrict__ cow, float* __restrict__ wt) {
  const int id = blockIdx.y;
  const int co_n = (id == 14) ? 64 : 128;
  const int nel = co_n * 1152;
  const int tid = blockIdx.x * 256 + threadIdx.x;
  if (tid >= nel) return;
  const float* src;
  if (id == 0) src = conv_w;
  else if (id == 1) src = convs_w;
  else if (id < 8) src = c1w + (size_t)(id - 2) * 147456u;
  else if (id < 14) src = c2w + (size_t)(id - 8) * 147456u;
  else src = cow;
  const int co = tid / 1152;
  const int rem = tid - co * 1152;
  const int ci = rem / 9;
  const int tap = rem - ci * 9;
  wt[WSLOT(id) + ((size_t)((tap * 32 + (ci >> 2)) * co_n + co) << 2) + (ci & 3)] = src[tid];
}

// ---------------------------------------------------------------------------
// Conv inner core: per-image implicit GEMM.
// xs4: padded 8x8x128 image as float4 [ (h*8+w)*32 + c4 ]
// wt4: [ (tap*32 + c4)*CO + co ] float4 (4 consecutive ci per co)
// Each thread: pixels p = tp + 8*j (j < np), c_outs co = tc + 32*k (k < NCO)
// x reads are same-address across each 32-lane half (LDS broadcast);
// weight reads are coalesced 512B global (L2-resident, ~576KB/layer).
// ---------------------------------------------------------------------------
template <int NCO>
__device__ __forceinline__ void conv_core(const float4* __restrict__ xs4,
                                          const float4* __restrict__ wt4,
                                          const int CO, const int tc, const int np,
                                          const int* ph, const int* pw,
                                          float (&acc)[5][NCO]) {
#pragma unroll
  for (int tap = 0; tap < 9; ++tap) {
    const int dy = tap / 3 - 1, dx = tap % 3 - 1;
    int qo[5];
#pragma unroll
    for (int j = 0; j < 5; ++j) qo[j] = ((ph[j] + 1 + dy) * 8 + (pw[j] + 1 + dx)) * 32;
    const float4* wrow = wt4 + (size_t)(tap * 32) * CO;
#pragma unroll 2
    for (int c4 = 0; c4 < 32; ++c4) {
      float4 w[NCO];
#pragma unroll
      for (int k = 0; k < NCO; ++k) w[k] = wrow[c4 * CO + tc + 32 * k];
#pragma unroll
      for (int j = 0; j < 5; ++j) {
        if (j < np) {
          float4 x = xs4[qo[j] + c4];
#pragma unroll
          for (int k = 0; k < NCO; ++k) {
            acc[j][k] = fmaf(x.x, w[k].x, acc[j][k]);
            acc[j][k] = fmaf(x.y, w[k].y, acc[j][k]);
            acc[j][k] = fmaf(x.z, w[k].z, acc[j][k]);
            acc[j][k] = fmaf(x.w, w[k].w, acc[j][k]);
          }
        }
      }
    }
  }
}

// ---------------------------------------------------------------------------
// Conv kernel. MODE 0: plain load. MODE 1: bn(stats,gamma,beta)+relu on load.
// MODE 2: bn + residual add(idn) + relu on load, write x back to xback.
// STATS: accumulate per-co sum/sumsq. OUTFLAT: write NCHW-flatten layout.
// ---------------------------------------------------------------------------
template <int MODE, int CO, int STATS, int OUTFLAT>
__global__ __launch_bounds__(256) void conv_kernel(
    const float* __restrict__ in, const float* __restrict__ idn,
    float* __restrict__ xback, const float* __restrict__ wt,
    const float* __restrict__ stats_in, const float* __restrict__ gamma,
    const float* __restrict__ beta, float* __restrict__ out,
    float* __restrict__ stats_out) {
  constexpr int NCO = CO / 32;
  __shared__ float xs[8192];
  __shared__ float As[128], Bs[128];
  __shared__ float red[2][8][CO];
  const int t = threadIdx.x, b = blockIdx.x;

  if (MODE >= 1 && t < 128) {
    float m = stats_in[t] * (1.0f / NTOT_);
    float var = stats_in[128 + t] * (1.0f / NTOT_) - m * m;
    float A = rsqrtf(var + EPS_) * gamma[t];
    As[t] = A;
    Bs[t] = fmaf(-m, A, beta[t]);
  }
  float4* xs4 = (float4*)xs;
  for (int i = t; i < 2048; i += 256) xs4[i] = make_float4(0.f, 0.f, 0.f, 0.f);
  __syncthreads();

  const float4* in4 = (const float4*)in;
  const float4* idn4 = (const float4*)idn;
  float4* xb4 = (float4*)xback;
  const float4* As4 = (const float4*)As;
  const float4* Bs4 = (const float4*)Bs;
  for (int e = t; e < 1152; e += 256) {
    int p = e >> 5, c4 = e & 31;
    size_t gi = (size_t)(b * 36 + p) * 32 + c4;
    float4 v = in4[gi];
    if (MODE >= 1) {
      float4 A = As4[c4], Bv = Bs4[c4];
      v.x = fmaf(v.x, A.x, Bv.x); v.y = fmaf(v.y, A.y, Bv.y);
      v.z = fmaf(v.z, A.z, Bv.z); v.w = fmaf(v.w, A.w, Bv.w);
      if (MODE == 2) {
        float4 d = idn4[gi];
        v.x += d.x; v.y += d.y; v.z += d.z; v.w += d.w;
      }
      v.x = fmaxf(v.x, 0.f); v.y = fmaxf(v.y, 0.f);
      v.z = fmaxf(v.z, 0.f); v.w = fmaxf(v.w, 0.f);
      if (MODE == 2) xb4[gi] = v;
    }
    int h = p / 6, w = p - h * 6;
    xs4[((h + 1) * 8 + (w + 1)) * 32 + c4] = v;
  }
  __syncthreads();

  const int tc = t & 31, tp = t >> 5;
  const int np = (tp < 4) ? 5 : 4;
  int ph[5], pw[5];
#pragma unroll
  for (int j = 0; j < 5; ++j) {
    int p = tp + 8 * j; if (p >= 36) p = 0;
    ph[j] = p / 6; pw[j] = p - ph[j] * 6;
  }
  float acc[5][NCO];
#pragma unroll
  for (int j = 0; j < 5; ++j)
#pragma unroll
    for (int k = 0; k < NCO; ++k) acc[j][k] = 0.f;

  conv_core<NCO>(xs4, (const float4*)wt, CO, tc, np, ph, pw, acc);

  float s[NCO], q[NCO];
#pragma unroll
  for (int k = 0; k < NCO; ++k) { s[k] = 0.f; q[k] = 0.f; }
#pragma unroll
  for (int j = 0; j < 5; ++j) {
    if (j < np) {
      const int p = tp + 8 * j;
#pragma unroll
      for (int k = 0; k < NCO; ++k) {
        const int co = tc + 32 * k;
        const float v = acc[j][k];
        if (OUTFLAT) out[(size_t)b * 2304 + co * 36 + p] = v;
        else out[((size_t)b * 36 + p) * CO + co] = v;
        s[k] += v; q[k] = fmaf(v, v, q[k]);
      }
    }
  }
  if (STATS) {
#pragma unroll
    for (int k = 0; k < NCO; ++k) {
      red[0][tp][tc + 32 * k] = s[k];
      red[1][tp][tc + 32 * k] = q[k];
    }
    __syncthreads();
    if (t < CO) {
      float ss = 0.f, qq = 0.f;
#pragma unroll
      for (int i = 0; i < 8; ++i) { ss += red[0][i][t]; qq += red[1][i][t]; }
      atomicAdd(&stats_out[t], ss);
      atomicAdd(&stats_out[128 + t], qq);
    }
  }
}

// ---------------------------------------------------------------------------
// Stem: x = relu(conv(s0,w0) + conv(s1,w1)); s0/s1 are NCHW fp32.
// ---------------------------------------------------------------------------
__global__ __launch_bounds__(256) void stem_kernel(
    const float* __restrict__ s0, const float* __restrict__ s1,
    const float* __restrict__ wt0, const float* __restrict__ wt1,
    float* __restrict__ out) {
  __shared__ float xs0[8192], xs1[8192];
  const int t = threadIdx.x, b = blockIdx.x;
  float4* a4 = (float4*)xs0;
  float4* b4 = (float4*)xs1;
  for (int i = t; i < 2048; i += 256) {
    a4[i] = make_float4(0.f, 0.f, 0.f, 0.f);
    b4[i] = make_float4(0.f, 0.f, 0.f, 0.f);
  }
  __syncthreads();
  for (int e = t; e < 4608; e += 256) {
    int c = e / 36, p = e - c * 36;
    int h = p / 6, w = p - h * 6;
    int li = ((h + 1) * 8 + (w + 1)) * 128 + c;
    xs0[li] = s0[(size_t)b * 4608 + e];
    xs1[li] = s1[(size_t)b * 4608 + e];
  }
  __syncthreads();
  const int tc = t & 31, tp = t >> 5;
  const int np = (tp < 4) ? 5 : 4;
  int ph[5], pw[5];
#pragma unroll
  for (int j = 0; j < 5; ++j) {
    int p = tp + 8 * j; if (p >= 36) p = 0;
    ph[j] = p / 6; pw[j] = p - ph[j] * 6;
  }
  float acc[5][4];
#pragma unroll
  for (int j = 0; j < 5; ++j)
#pragma unroll
    for (int k = 0; k < 4; ++k) acc[j][k] = 0.f;
  conv_core<4>((const float4*)xs0, (const float4*)wt0, 128, tc, np, ph, pw, acc);
  conv_core<4>((const float4*)xs1, (const float4*)wt1, 128, tc, np, ph, pw, acc);
#pragma unroll
  for (int j = 0; j < 5; ++j) {
    if (j < np) {
      const int p = tp + 8 * j;
#pragma unroll
      for (int k = 0; k < 4; ++k)
        out[((size_t)b * 36 + p) * 128 + tc + 32 * k] = fmaxf(acc[j][k], 0.f);
    }
  }
}

// ---------------------------------------------------------------------------
// FC: out[b][e] += flat[b][:] . fc_w[e][:]   (K split over grid.y, atomics)
// ---------------------------------------------------------------------------
__global__ __launch_bounds__(256) void fc_kernel(
    const float* __restrict__ flat, const float* __restrict__ fcw,
    float* __restrict__ out) {
  __shared__ float fs[32 * 384];
  const int t = threadIdx.x;
  const int b0 = blockIdx.x * 32;
  const int k04 = blockIdx.y * 96;  // float4 units within row of 576
  float4* fs4 = (float4*)fs;
  const float4* fl4 = (const float4*)flat;
  for (int i = t; i < 3072; i += 256) {
    int r = i / 96, k = i - r * 96;
    fs4[i] = fl4[(size_t)(b0 + r) * 576 + k04 + k];
  }
  __syncthreads();
  const int tc = t & 31, tp = t >> 5;
  const float4* fw4 = (const float4*)fcw;
  float acc[4][4];
#pragma unroll
  for (int r = 0; r < 4; ++r)
#pragma unroll
    for (int j = 0; j < 4; ++j) acc[r][j] = 0.f;
  for (int k = 0; k < 96; ++k) {
    float4 w[4];
#pragma unroll
    for (int j = 0; j < 4; ++j) w[j] = fw4[(size_t)(tc + 32 * j) * 576 + k04 + k];
    float4 x[4];
#pragma unroll
    for (int r = 0; r < 4; ++r) x[r] = fs4[(tp * 4 + r) * 96 + k];
#pragma unroll
    for (int r = 0; r < 4; ++r)
#pragma unroll
      for (int j = 0; j < 4; ++j) {
        acc[r][j] = fmaf(x[r].x, w[j].x, acc[r][j]);
        acc[r][j] = fmaf(x[r].y, w[j].y, acc[r][j]);
        acc[r][j] = fmaf(x[r].z, w[j].z, acc[r][j]);
        acc[r][j] = fmaf(x[r].w, w[j].w, acc[r][j]);
      }
  }
#pragma unroll
  for (int r = 0; r < 4; ++r)
#pragma unroll
    for (int j = 0; j < 4; ++j)
      atomicAdd(&out[(size_t)(b0 + tp * 4 + r) * 128 + tc + 32 * j], acc[r][j]);
}

// per-feature sum / sumsq over batch (for bn_o)
__global__ __launch_bounds__(64) void fcstats_kernel(const float* __restrict__ fco,
                                                     float* __restrict__ st) {
  const int e = blockIdx.x, l = threadIdx.x;
  float s = 0.f, q = 0.f;
  for (int b = l; b < 512; b += 64) {
    float v = fco[(size_t)b * 128 + e];
    s += v; q = fmaf(v, v, q);
  }
  for (int off = 32; off; off >>= 1) {
    s += __shfl_down(s, off);
    q += __shfl_down(q, off);
  }
  if (l == 0) { st[e] = s; st[128 + e] = q; }
}

// ---------------------------------------------------------------------------
// VQ: bn_o normalize, nearest code (argmin, first-min tie rule), loss, z, idx
// ---------------------------------------------------------------------------
__global__ __launch_bounds__(256) void vq_kernel(
    const float* __restrict__ fco, const float* __restrict__ st,
    const float* __restrict__ emb, float* __restrict__ dout) {
  __shared__ float fn[128], qv[128];
  __shared__ unsigned long long wmin[4];
  __shared__ float lred[2];
  const int t = threadIdx.x, b = blockIdx.x;
  if (t < 128) {
    float m = st[t] * (1.0f / 512.0f);
    float var = st[128 + t] * (1.0f / 512.0f) - m * m;
    float rs = rsqrtf(var + EPS_);
    fn[t] = (fco[(size_t)b * 128 + t] - m) * rs;
  }
  __syncthreads();
  const float4* e4 = (const float4*)emb;
  const float4* f4 = (const float4*)fn;
  unsigned long long best = ~0ull;
  for (int k = t; k < 512; k += 256) {
    float d = 0.f;
#pragma unroll 4
    for (int j = 0; j < 32; ++j) {
      float4 e = e4[(size_t)k * 32 + j];
      float4 f = f4[j];
      float dx = f.x - e.x, dy = f.y - e.y, dz = f.z - e.z, dw = f.w - e.w;
      d = fmaf(dx, dx, d); d = fmaf(dy, dy, d);
      d = fmaf(dz, dz, d); d = fmaf(dw, dw, d);
    }
    unsigned long long key = ((unsigned long long)__float_as_uint(d) << 32) | (unsigned)k;
    if (key < best) best = key;
  }
  for (int off = 32; off; off >>= 1) {
    unsigned long long o = __shfl_down(best, off);
    if (o < best) best = o;
  }
  if ((t & 63) == 0) wmin[t >> 6] = best;
  __syncthreads();
  if (t == 0) {
    unsigned long long m01 = wmin[0] < wmin[1] ? wmin[0] : wmin[1];
    unsigned long long m23 = wmin[2] < wmin[3] ? wmin[2] : wmin[3];
    wmin[0] = m01 < m23 ? m01 : m23;
  }
  __syncthreads();
  const int ks = (int)(wmin[0] & 0xffffffffu);
  if (t < 128) qv[t] = emb[(size_t)ks * 128 + t];
  __syncthreads();
  if (t < 128) {
    float df = qv[t] - fn[t];
    float sq = df * df;
    for (int off = 32; off; off >>= 1) sq += __shfl_down(sq, off);
    if ((t & 63) == 0) lred[t >> 6] = sq;
  }
  __syncthreads();
  if (t == 0) dout[LOSS_OFF + b] = (lred[0] + lred[1]) * (2.0f / 128.0f);
  // z = broadcast q to [b][128][6][6]
  float4* z4 = (float4*)dout;
  for (int i = t; i < 1152; i += 256) {
    int e = i / 9, j = i - e * 9;
    float v = qv[e];
    z4[((size_t)b * 128 + e) * 9 + j] = make_float4(v, v, v, v);
  }
  if (t == 0) dout[IDX_OFF + b] = (float)ks;
}

__global__ __launch_bounds__(512) void perp_kernel(float* __restrict__ dout) {
  __shared__ int hist[512];
  __shared__ float wr[8];
  const int t = threadIdx.x;
  hist[t] = 0;
  __syncthreads();
  int k = (int)dout[IDX_OFF + t];
  atomicAdd(&hist[k], 1);
  __syncthreads();
  float p = hist[t] * (1.0f / 512.0f);
  float term = p * logf(p + 1e-10f);
  for (int off = 32; off; off >>= 1) term += __shfl_down(term, off);
  if ((t & 63) == 0) wr[t >> 6] = term;
  __syncthreads();
  if (t == 0) {
    float s = 0.f;
#pragma unroll
    for (int i = 0; i < 8; ++i) s += wr[i];
    dout[PERP_OFF] = expf(-s);
  }
}

// ---------------------------------------------------------------------------
extern "C" void kernel_launch(void* const* d_in, const int* in_sizes, int n_in,
                              void* d_out, int out_size, void* d_ws, size_t ws_size,
                              hipStream_t stream) {
  const float* s0        = (const float*)d_in[0];
  const float* s1        = (const float*)d_in[1];
  const float* conv_w    = (const float*)d_in[2];
  const float* convs_w   = (const float*)d_in[3];
  const float* rb_c1_w   = (const float*)d_in[4];
  const float* rb_bn1_s  = (const float*)d_in[5];
  const float* rb_bn1_b  = (const float*)d_in[6];
  const float* rb_c2_w   = (const float*)d_in[7];
  const float* rb_bn2_s  = (const float*)d_in[8];
  const float* rb_bn2_b  = (const float*)d_in[9];
  const float* conv_out_w= (const float*)d_in[10];
  const float* fc_w      = (const float*)d_in[11];
  // d_in[12] = fc_b: cancels under bn_o mean subtraction -> unused
  const float* emb       = (const float*)d_in[13];

  float* ws   = (float*)d_ws;
  float* wt   = ws;
  float* bufA = ws + BUFA_OFF;
  float* bufB = ws + BUFB_OFF;
  float* bufC = ws + BUFC_OFF;
  float* flat = ws + FLAT_OFF;
  float* fco  = ws + FCO_OFF;
  float* stats= ws + STATS_OFF;
  float* out  = (float*)d_out;

  // zero the atomic accumulators (fc out + all BN stats), single memset node
  hipMemsetAsync(fco, 0, (65536 + 3328) * sizeof(float), stream);

  prep_weights<<<dim3(576, 15), 256, 0, stream>>>(conv_w, convs_w, rb_c1_w,
                                                  rb_c2_w, conv_out_w, wt);
  stem_kernel<<<512, 256, 0, stream>>>(s0, s1, wt, wt + WSLOT(1), bufA);

  for (int i = 0; i < 6; ++i) {
    float* st1 = stats + (size_t)(2 * i) * 256;
    float* st2 = stats + (size_t)(2 * i + 1) * 256;
    if (i == 0) {
      conv_kernel<0, 128, 1, 0><<<512, 256, 0, stream>>>(
          bufA, nullptr, nullptr, wt + WSLOT(2), nullptr, nullptr, nullptr,
          bufB, st1);
    } else {
      conv_kernel<2, 128, 1, 0><<<512, 256, 0, stream>>>(
          bufC, bufA, bufA, wt + WSLOT(2 + i), stats + (size_t)(2 * i - 1) * 256,
          rb_bn2_s + (size_t)(i - 1) * 128, rb_bn2_b + (size_t)(i - 1) * 128,
          bufB, st1);
    }
    conv_kernel<1, 128, 1, 0><<<512, 256, 0, stream>>>(
        bufB, nullptr, nullptr, wt + WSLOT(8 + i), st1,
        rb_bn1_s + (size_t)i * 128, rb_bn1_b + (size_t)i * 128, bufC, st2);
  }

  // conv_out: bn2(block5) + add + relu fused on load; writes NCHW-flatten
  conv_kernel<2, 64, 0, 1><<<512, 256, 0, stream>>>(
      bufC, bufA, bufA, wt + WSLOT(14), stats + 11u * 256,
      rb_bn2_s + 5u * 128, rb_bn2_b + 5u * 128, flat, nullptr);

  fc_kernel<<<dim3(16, 6), 256, 0, stream>>>(flat, fc_w, fco);
  fcstats_kernel<<<128, 64, 0, stream>>>(fco, stats + 12u * 256);
  vq_kernel<<<512, 256, 0, stream>>>(fco, stats + 12u * 256, emb, out);
  perp_kernel<<<1, 512, 0, stream>>>(out);
}

// Round 6
// 808.410 us; speedup vs baseline: 2.4543x; 2.4543x over previous
//
#include <hip/hip_runtime.h>
#include <cstdint>
#include <cstddef>

// ---------------------------------------------------------------------------
// LatentActionGen forward on MI355X — round 6: byte-identical resubmit of
// round-4/5 MFMA conv tower (GPU never acquired in rounds 3/4/5).
//
// memset -> prep_wb -> stem_mfma -> 6x{c1,c2} -> conv_out -> fc -> fcstats
// -> vq -> perp
//
// Convs: per-image implicit GEMM on mfma_f32_16x16x32_bf16 with 3-plane
// bf16 split of both operands, 6 MFMAs per product pair (~fp32 precision).
// Activations NHWC fp32 between layers; A-tile staged in LDS as 3 bf16
// planes (padded 8x8 + zero guard rows, XOR-swizzled 16B slots). Weights
// pre-transformed once into exact B-fragment chunk order. BN(training)/
// residual/relu fused at consumer staging; producer accumulates per-channel
// sum/sumsq (dummy rows contribute exact zeros).
// ---------------------------------------------------------------------------

typedef __attribute__((ext_vector_type(8))) short bf16x8;
typedef __attribute__((ext_vector_type(4))) float f32x4;

#define EPS_  1e-5f
#define NTOT_ 18432.0f

// ws float offsets
#define BUFA_OFF  3207168u   // wb = 12528 chunks * 1KB = 12528 KB
#define BUFB_OFF  5566464u
#define BUFC_OFF  7925760u
#define FLAT_OFF  BUFB_OFF   // flat aliases bufB (dead by conv_out)
#define FCO_OFF   10285056u
#define STATS_OFF 10350592u
// total 10353920 floats = 41.4 MB

// d_out offsets (floats)
#define LOSS_OFF 2359296u
#define PERP_OFF 2359808u
#define IDX_OFF  2359809u

__device__ __forceinline__ unsigned short f2bf(float v) {
  unsigned u = __float_as_uint(v);
  return (unsigned short)((u + 0x7fffu + ((u >> 16) & 1u)) >> 16);
}
__device__ __forceinline__ float bf2f(unsigned short h) {
  return __uint_as_float((unsigned)h << 16);
}
// swizzled 16B-slot index within plane; mixes row bits into bank bits
__device__ __forceinline__ int swz16(int pr, int cio) {
  return (pr * 16 + cio) ^ ((pr ^ (pr >> 3)) & 7);
}

#define MF(Aa, Bb, Cc) Cc = __builtin_amdgcn_mfma_f32_16x16x32_bf16(Aa, Bb, Cc, 0, 0, 0)

// ---------------------------------------------------------------------------
// Weight prep: B-frag chunks. chunk = 64 lanes x 16B (8 bf16); lane l holds
// W[k = ks*32 + (l>>4)*8 + j][n = nt*16 + (l&15)], one chunk per plane.
//   stem:  (nt*72 + ks)*3 + p               [ks<36: conv_w, else convs_w]
//   tower: 1728 + ((L*8+nt)*36 + ks)*3 + p  [L<6: c1[L], else c2[L-6]]
//   cout:  12096 + (nt*36 + ks)*3 + p
// ---------------------------------------------------------------------------
__global__ __launch_bounds__(256) void prep_wb(
    const float* __restrict__ conv_w, const float* __restrict__ convs_w,
    const float* __restrict__ c1w, const float* __restrict__ c2w,
    const float* __restrict__ cow, uint4* __restrict__ wb) {
  const int ct = blockIdx.x * 4 + (threadIdx.x >> 6);
  const int lane = threadIdx.x & 63;
  const float* src;
  int n, ks_eff, chbase;
  if (ct < 576) {
    int ks = ct % 72;
    src = (ks < 36) ? conv_w : convs_w;
    ks_eff = (ks < 36) ? ks : ks - 36;
    n = (ct / 72) * 16 + (lane & 15);
    chbase = ct * 3;
  } else if (ct < 4032) {
    int q = ct - 576;
    int L = q / 288, r = q % 288;
    src = (L < 6) ? (c1w + (size_t)L * 147456u) : (c2w + (size_t)(L - 6) * 147456u);
    ks_eff = r % 36;
    n = (r / 36) * 16 + (lane & 15);
    chbase = 1728 + q * 3;
  } else {
    int q = ct - 4032;
    src = cow;
    ks_eff = q % 36;
    n = (q / 36) * 16 + (lane & 15);
    chbase = 12096 + q * 3;
  }
  const int tap = ks_eff >> 2;
  const int ci0 = (ks_eff & 3) * 32 + (lane >> 4) * 8;
  uint4 q1, q2, q3;
  unsigned* u1 = (unsigned*)&q1;
  unsigned* u2 = (unsigned*)&q2;
  unsigned* u3 = (unsigned*)&q3;
#pragma unroll
  for (int j = 0; j < 4; ++j) {
    float va = src[((size_t)n * 128 + ci0 + 2 * j) * 9 + tap];
    float vb = src[((size_t)n * 128 + ci0 + 2 * j + 1) * 9 + tap];
    unsigned short a1 = f2bf(va), b1 = f2bf(vb);
    float ra = va - bf2f(a1), rb = vb - bf2f(b1);
    unsigned short a2 = f2bf(ra), b2 = f2bf(rb);
    ra -= bf2f(a2); rb -= bf2f(b2);
    u1[j] = (unsigned)a1 | ((unsigned)b1 << 16);
    u2[j] = (unsigned)a2 | ((unsigned)b2 << 16);
    u3[j] = (unsigned)f2bf(ra) | ((unsigned)f2bf(rb) << 16);
  }
  wb[(size_t)(chbase + 0) * 64 + lane] = q1;
  wb[(size_t)(chbase + 1) * 64 + lane] = q2;
  wb[(size_t)(chbase + 2) * 64 + lane] = q3;
}

// ---------------------------------------------------------------------------
// MFMA conv layer. Block = 1 image. LDS: 3 planes x 88 rows x 128 ci bf16
// (row 0..8 pad, 9..54 interior, 55..63 pad, 64..87 zero guard for dummies).
// ---------------------------------------------------------------------------
template <int MODE, int NTILES, int STATS, int OUTFLAT>
__global__ __launch_bounds__(256) void conv_mfma(
    const float* __restrict__ in, const float* __restrict__ idn,
    float* __restrict__ xback, const uint4* __restrict__ wbL,
    const float* __restrict__ stats_in, const float* __restrict__ gamma,
    const float* __restrict__ beta, float* __restrict__ out,
    float* __restrict__ stats_out) {
  constexpr int NTPW = NTILES / 4;
  __shared__ __align__(16) unsigned short apl[3 * 11264];
  __shared__ __align__(16) float As[128], Bs[128];
  const int t = threadIdx.x, b = blockIdx.x;

  if (MODE >= 1 && t < 128) {
    float m = stats_in[t] * (1.0f / NTOT_);
    float var = stats_in[128 + t] * (1.0f / NTOT_) - m * m;
    float A = rsqrtf(var + EPS_) * gamma[t];
    As[t] = A;
    Bs[t] = fmaf(-m, A, beta[t]);
  }
  uint4* z4 = (uint4*)apl;
  for (int i = t; i < 4224; i += 256) z4[i] = make_uint4(0, 0, 0, 0);
  __syncthreads();

  const float4* in4 = (const float4*)in;
  const float4* idn4 = (const float4*)idn;
  float4* xb4 = (float4*)xback;
  const float4* As4 = (const float4*)As;
  const float4* Bs4 = (const float4*)Bs;
  for (int e = t; e < 576; e += 256) {
    int px = e >> 4, cich = e & 15;
    size_t gi = (size_t)(b * 36 + px) * 32 + cich * 2;
    float4 v0 = in4[gi], v1 = in4[gi + 1];
    if (MODE >= 1) {
      float4 A0 = As4[cich * 2], B0 = Bs4[cich * 2];
      float4 A1 = As4[cich * 2 + 1], B1 = Bs4[cich * 2 + 1];
      v0.x = fmaf(v0.x, A0.x, B0.x); v0.y = fmaf(v0.y, A0.y, B0.y);
      v0.z = fmaf(v0.z, A0.z, B0.z); v0.w = fmaf(v0.w, A0.w, B0.w);
      v1.x = fmaf(v1.x, A1.x, B1.x); v1.y = fmaf(v1.y, A1.y, B1.y);
      v1.z = fmaf(v1.z, A1.z, B1.z); v1.w = fmaf(v1.w, A1.w, B1.w);
      if (MODE == 2) {
        float4 d0 = idn4[gi], d1 = idn4[gi + 1];
        v0.x += d0.x; v0.y += d0.y; v0.z += d0.z; v0.w += d0.w;
        v1.x += d1.x; v1.y += d1.y; v1.z += d1.z; v1.w += d1.w;
      }
      v0.x = fmaxf(v0.x, 0.f); v0.y = fmaxf(v0.y, 0.f);
      v0.z = fmaxf(v0.z, 0.f); v0.w = fmaxf(v0.w, 0.f);
      v1.x = fmaxf(v1.x, 0.f); v1.y = fmaxf(v1.y, 0.f);
      v1.z = fmaxf(v1.z, 0.f); v1.w = fmaxf(v1.w, 0.f);
      if (MODE == 2) { xb4[gi] = v0; xb4[gi + 1] = v1; }
    }
    float vv[8] = {v0.x, v0.y, v0.z, v0.w, v1.x, v1.y, v1.z, v1.w};
    uint4 q1, q2, q3;
    unsigned* u1 = (unsigned*)&q1;
    unsigned* u2 = (unsigned*)&q2;
    unsigned* u3 = (unsigned*)&q3;
#pragma unroll
    for (int j = 0; j < 4; ++j) {
      unsigned short a1 = f2bf(vv[2 * j]), b1 = f2bf(vv[2 * j + 1]);
      float ra = vv[2 * j] - bf2f(a1), rb = vv[2 * j + 1] - bf2f(b1);
      unsigned short a2 = f2bf(ra), b2 = f2bf(rb);
      ra -= bf2f(a2); rb -= bf2f(b2);
      u1[j] = (unsigned)a1 | ((unsigned)b1 << 16);
      u2[j] = (unsigned)a2 | ((unsigned)b2 << 16);
      u3[j] = (unsigned)f2bf(ra) | ((unsigned)f2bf(rb) << 16);
    }
    int hh = px / 6, ww = px - hh * 6;
    int pp = (hh + 1) * 8 + (ww + 1);
    int a16 = swz16(pp, cich);
    z4[0 * 1408 + a16] = q1;
    z4[1 * 1408 + a16] = q2;
    z4[2 * 1408 + a16] = q3;
  }
  __syncthreads();

  const int wave = t >> 6, lane = t & 63;
  const int l15 = lane & 15, kq = lane >> 4;
  int ppb[3];
#pragma unroll
  for (int mt = 0; mt < 3; ++mt) {
    int px = mt * 16 + l15;
    ppb[mt] = (px < 36) ? ((px / 6 + 1) * 8 + (px % 6) + 1) : 73;
  }
  f32x4 zz = {0.f, 0.f, 0.f, 0.f};
  f32x4 acc[3][NTPW];
#pragma unroll
  for (int mt = 0; mt < 3; ++mt)
#pragma unroll
    for (int n2 = 0; n2 < NTPW; ++n2) acc[mt][n2] = zz;

  for (int tap = 0; tap < 9; ++tap) {
    const int dyx = (tap / 3 - 1) * 8 + (tap % 3) - 1;
#pragma unroll
    for (int kc = 0; kc < 4; ++kc) {
      const int ks = tap * 4 + kc;
      bf16x8 bfr[NTPW][3];
#pragma unroll
      for (int n2 = 0; n2 < NTPW; ++n2)
#pragma unroll
        for (int pl = 0; pl < 3; ++pl)
          bfr[n2][pl] = __builtin_bit_cast(bf16x8,
              wbL[((size_t)((wave * NTPW + n2) * 36 + ks) * 3 + pl) * 64 + lane]);
      bf16x8 afr[3][3];
#pragma unroll
      for (int mt = 0; mt < 3; ++mt) {
        int pr = ppb[mt] + dyx;
        int a16 = swz16(pr, kc * 4 + kq);
#pragma unroll
        for (int pl = 0; pl < 3; ++pl)
          afr[mt][pl] = *(const bf16x8*)(apl + pl * 11264 + a16 * 8);
      }
#pragma unroll
      for (int mt = 0; mt < 3; ++mt)
#pragma unroll
        for (int n2 = 0; n2 < NTPW; ++n2) {
          MF(afr[mt][0], bfr[n2][0], acc[mt][n2]);
          MF(afr[mt][1], bfr[n2][0], acc[mt][n2]);
          MF(afr[mt][0], bfr[n2][1], acc[mt][n2]);
          MF(afr[mt][2], bfr[n2][0], acc[mt][n2]);
          MF(afr[mt][1], bfr[n2][1], acc[mt][n2]);
          MF(afr[mt][0], bfr[n2][2], acc[mt][n2]);
        }
    }
  }

  float s[NTPW], sq[NTPW];
#pragma unroll
  for (int n2 = 0; n2 < NTPW; ++n2) { s[n2] = 0.f; sq[n2] = 0.f; }
#pragma unroll
  for (int mt = 0; mt < 3; ++mt)
#pragma unroll
    for (int n2 = 0; n2 < NTPW; ++n2) {
      const int cc = (wave * NTPW + n2) * 16 + l15;
#pragma unroll
      for (int q = 0; q < 4; ++q) {
        int px = mt * 16 + kq * 4 + q;
        float v = acc[mt][n2][q];
        if (px < 36) {
          if (OUTFLAT) out[(size_t)b * 2304 + cc * 36 + px] = v;
          else out[((size_t)b * 36 + px) * 128 + cc] = v;
        }
        s[n2] += v; sq[n2] = fmaf(v, v, sq[n2]);
      }
    }
  if (STATS) {
#pragma unroll
    for (int n2 = 0; n2 < NTPW; ++n2) {
      float sv = s[n2], qv = sq[n2];
      sv += __shfl_xor(sv, 16); qv += __shfl_xor(qv, 16);
      sv += __shfl_xor(sv, 32); qv += __shfl_xor(qv, 32);
      if (kq == 0) {
        const int cc = (wave * NTPW + n2) * 16 + l15;
        atomicAdd(&stats_out[cc], sv);
        atomicAdd(&stats_out[128 + cc], qv);
      }
    }
  }
}

// ---------------------------------------------------------------------------
// Stem: relu(conv(s0,w0)+conv(s1,w1)) as one K=2304 GEMM. 6 LDS planes.
// ---------------------------------------------------------------------------
__global__ __launch_bounds__(256) void stem_mfma(
    const float* __restrict__ s0, const float* __restrict__ s1,
    const uint4* __restrict__ wbL, float* __restrict__ out) {
  __shared__ __align__(16) unsigned short apl[6 * 11264];
  const int t = threadIdx.x, b = blockIdx.x;
  uint4* z4 = (uint4*)apl;
  for (int i = t; i < 8448; i += 256) z4[i] = make_uint4(0, 0, 0, 0);
  __syncthreads();
  for (int e = t; e < 4608; e += 256) {
    int c = e / 36, px = e - c * 36;
    int hh = px / 6, ww = px - hh * 6;
    int pp = (hh + 1) * 8 + (ww + 1);
    int sw = swz16(pp, c >> 3) * 8 + (c & 7);
    float v0 = s0[(size_t)b * 4608 + e], v1 = s1[(size_t)b * 4608 + e];
    unsigned short h; float r;
    h = f2bf(v0); apl[0 * 11264 + sw] = h; r = v0 - bf2f(h);
    h = f2bf(r);  apl[1 * 11264 + sw] = h; r -= bf2f(h);
    apl[2 * 11264 + sw] = f2bf(r);
    h = f2bf(v1); apl[3 * 11264 + sw] = h; r = v1 - bf2f(h);
    h = f2bf(r);  apl[4 * 11264 + sw] = h; r -= bf2f(h);
    apl[5 * 11264 + sw] = f2bf(r);
  }
  __syncthreads();

  const int wave = t >> 6, lane = t & 63;
  const int l15 = lane & 15, kq = lane >> 4;
  int ppb[3];
#pragma unroll
  for (int mt = 0; mt < 3; ++mt) {
    int px = mt * 16 + l15;
    ppb[mt] = (px < 36) ? ((px / 6 + 1) * 8 + (px % 6) + 1) : 73;
  }
  f32x4 zz = {0.f, 0.f, 0.f, 0.f};
  f32x4 acc[3][2];
#pragma unroll
  for (int mt = 0; mt < 3; ++mt) { acc[mt][0] = zz; acc[mt][1] = zz; }

  for (int half = 0; half < 2; ++half) {
    const unsigned short* ap = apl + half * 3 * 11264;
    for (int tap = 0; tap < 9; ++tap) {
      const int dyx = (tap / 3 - 1) * 8 + (tap % 3) - 1;
#pragma unroll
      for (int kc = 0; kc < 4; ++kc) {
        const int ks = half * 36 + tap * 4 + kc;
        bf16x8 bfr[2][3];
#pragma unroll
        for (int n2 = 0; n2 < 2; ++n2)
#pragma unroll
          for (int pl = 0; pl < 3; ++pl)
            bfr[n2][pl] = __builtin_bit_cast(bf16x8,
                wbL[((size_t)((wave * 2 + n2) * 72 + ks) * 3 + pl) * 64 + lane]);
        bf16x8 afr[3][3];
#pragma unroll
        for (int mt = 0; mt < 3; ++mt) {
          int pr = ppb[mt] + dyx;
          int a16 = swz16(pr, kc * 4 + kq);
#pragma unroll
          for (int pl = 0; pl < 3; ++pl)
            afr[mt][pl] = *(const bf16x8*)(ap + pl * 11264 + a16 * 8);
        }
#pragma unroll
        for (int mt = 0; mt < 3; ++mt)
#pragma unroll
          for (int n2 = 0; n2 < 2; ++n2) {
            MF(afr[mt][0], bfr[n2][0], acc[mt][n2]);
            MF(afr[mt][1], bfr[n2][0], acc[mt][n2]);
            MF(afr[mt][0], bfr[n2][1], acc[mt][n2]);
            MF(afr[mt][2], bfr[n2][0], acc[mt][n2]);
            MF(afr[mt][1], bfr[n2][1], acc[mt][n2]);
            MF(afr[mt][0], bfr[n2][2], acc[mt][n2]);
          }
      }
    }
  }
#pragma unroll
  for (int mt = 0; mt < 3; ++mt)
#pragma unroll
    for (int n2 = 0; n2 < 2; ++n2) {
      const int cc = (wave * 2 + n2) * 16 + l15;
#pragma unroll
      for (int q = 0; q < 4; ++q) {
        int px = mt * 16 + kq * 4 + q;
        if (px < 36)
          out[((size_t)b * 36 + px) * 128 + cc] = fmaxf(acc[mt][n2][q], 0.f);
      }
    }
}

// ---------------------------------------------------------------------------
// FC / stats / VQ / perplexity (unchanged from validated fp32 round)
// ---------------------------------------------------------------------------
__global__ __launch_bounds__(256) void fc_kernel(
    const float* __restrict__ flat, const float* __restrict__ fcw,
    float* __restrict__ out) {
  __shared__ __align__(16) float fs[32 * 384];
  const int t = threadIdx.x;
  const int b0 = blockIdx.x * 32;
  const int k04 = blockIdx.y * 96;
  float4* fs4 = (float4*)fs;
  const float4* fl4 = (const float4*)flat;
  for (int i = t; i < 3072; i += 256) {
    int r = i / 96, k = i - r * 96;
    fs4[i] = fl4[(size_t)(b0 + r) * 576 + k04 + k];
  }
  __syncthreads();
  const int tc = t & 31, tp = t >> 5;
  const float4* fw4 = (const float4*)fcw;
  float acc[4][4];
#pragma unroll
  for (int r = 0; r < 4; ++r)
#pragma unroll
    for (int j = 0; j < 4; ++j) acc[r][j] = 0.f;
  for (int k = 0; k < 96; ++k) {
    float4 w[4];
#pragma unroll
    for (int j = 0; j < 4; ++j) w[j] = fw4[(size_t)(tc + 32 * j) * 576 + k04 + k];
    float4 x[4];
#pragma unroll
    for (int r = 0; r < 4; ++r) x[r] = fs4[(tp * 4 + r) * 96 + k];
#pragma unroll
    for (int r = 0; r < 4; ++r)
#pragma unroll
      for (int j = 0; j < 4; ++j) {
        acc[r][j] = fmaf(x[r].x, w[j].x, acc[r][j]);
        acc[r][j] = fmaf(x[r].y, w[j].y, acc[r][j]);
        acc[r][j] = fmaf(x[r].z, w[j].z, acc[r][j]);
        acc[r][j] = fmaf(x[r].w, w[j].w, acc[r][j]);
      }
  }
#pragma unroll
  for (int r = 0; r < 4; ++r)
#pragma unroll
    for (int j = 0; j < 4; ++j)
      atomicAdd(&out[(size_t)(b0 + tp * 4 + r) * 128 + tc + 32 * j], acc[r][j]);
}

__global__ __launch_bounds__(64) void fcstats_kernel(const float* __restrict__ fco,
                                                     float* __restrict__ st) {
  const int e = blockIdx.x, l = threadIdx.x;
  float s = 0.f, q = 0.f;
  for (int b = l; b < 512; b += 64) {
    float v = fco[(size_t)b * 128 + e];
    s += v; q = fmaf(v, v, q);
  }
  for (int off = 32; off; off >>= 1) {
    s += __shfl_down(s, off);
    q += __shfl_down(q, off);
  }
  if (l == 0) { st[e] = s; st[128 + e] = q; }
}

__global__ __launch_bounds__(256) void vq_kernel(
    const float* __restrict__ fco, const float* __restrict__ st,
    const float* __restrict__ emb, float* __restrict__ dout) {
  __shared__ __align__(16) float fn[128], qv[128];
  __shared__ unsigned long long wmin[4];
  __shared__ float lred[2];
  const int t = threadIdx.x, b = blockIdx.x;
  if (t < 128) {
    float m = st[t] * (1.0f / 512.0f);
    float var = st[128 + t] * (1.0f / 512.0f) - m * m;
    float rs = rsqrtf(var + EPS_);
    fn[t] = (fco[(size_t)b * 128 + t] - m) * rs;
  }
  __syncthreads();
  const float4* e4 = (const float4*)emb;
  const float4* f4 = (const float4*)fn;
  unsigned long long best = ~0ull;
  for (int k = t; k < 512; k += 256) {
    float d = 0.f;
#pragma unroll 4
    for (int j = 0; j < 32; ++j) {
      float4 e = e4[(size_t)k * 32 + j];
      float4 f = f4[j];
      float dx = f.x - e.x, dy = f.y - e.y, dz = f.z - e.z, dw = f.w - e.w;
      d = fmaf(dx, dx, d); d = fmaf(dy, dy, d);
      d = fmaf(dz, dz, d); d = fmaf(dw, dw, d);
    }
    unsigned long long key = ((unsigned long long)__float_as_uint(d) << 32) | (unsigned)k;
    if (key < best) best = key;
  }
  for (int off = 32; off; off >>= 1) {
    unsigned long long o = __shfl_down(best, off);
    if (o < best) best = o;
  }
  if ((t & 63) == 0) wmin[t >> 6] = best;
  __syncthreads();
  if (t == 0) {
    unsigned long long m01 = wmin[0] < wmin[1] ? wmin[0] : wmin[1];
    unsigned long long m23 = wmin[2] < wmin[3] ? wmin[2] : wmin[3];
    wmin[0] = m01 < m23 ? m01 : m23;
  }
  __syncthreads();
  const int ks = (int)(wmin[0] & 0xffffffffu);
  if (t < 128) qv[t] = emb[(size_t)ks * 128 + t];
  __syncthreads();
  if (t < 128) {
    float df = qv[t] - fn[t];
    float sq = df * df;
    for (int off = 32; off; off >>= 1) sq += __shfl_down(sq, off);
    if ((t & 63) == 0) lred[t >> 6] = sq;
  }
  __syncthreads();
  if (t == 0) dout[LOSS_OFF + b] = (lred[0] + lred[1]) * (2.0f / 128.0f);
  float4* z4 = (float4*)dout;
  for (int i = t; i < 1152; i += 256) {
    int e = i / 9, j = i - e * 9;
    float v = qv[e];
    z4[((size_t)b * 128 + e) * 9 + j] = make_float4(v, v, v, v);
  }
  if (t == 0) dout[IDX_OFF + b] = (float)ks;
}

__global__ __launch_bounds__(512) void perp_kernel(float* __restrict__ dout) {
  __shared__ int hist[512];
  __shared__ float wr[8];
  const int t = threadIdx.x;
  hist[t] = 0;
  __syncthreads();
  int k = (int)dout[IDX_OFF + t];
  atomicAdd(&hist[k], 1);
  __syncthreads();
  float p = hist[t] * (1.0f / 512.0f);
  float term = p * logf(p + 1e-10f);
  for (int off = 32; off; off >>= 1) term += __shfl_down(term, off);
  if ((t & 63) == 0) wr[t >> 6] = term;
  __syncthreads();
  if (t == 0) {
    float s = 0.f;
#pragma unroll
    for (int i = 0; i < 8; ++i) s += wr[i];
    dout[PERP_OFF] = expf(-s);
  }
}

// ---------------------------------------------------------------------------
extern "C" void kernel_launch(void* const* d_in, const int* in_sizes, int n_in,
                              void* d_out, int out_size, void* d_ws, size_t ws_size,
                              hipStream_t stream) {
  const float* s0        = (const float*)d_in[0];
  const float* s1        = (const float*)d_in[1];
  const float* conv_w    = (const float*)d_in[2];
  const float* convs_w   = (const float*)d_in[3];
  const float* rb_c1_w   = (const float*)d_in[4];
  const float* rb_bn1_s  = (const float*)d_in[5];
  const float* rb_bn1_b  = (const float*)d_in[6];
  const float* rb_c2_w   = (const float*)d_in[7];
  const float* rb_bn2_s  = (const float*)d_in[8];
  const float* rb_bn2_b  = (const float*)d_in[9];
  const float* conv_out_w= (const float*)d_in[10];
  const float* fc_w      = (const float*)d_in[11];
  // d_in[12] = fc_b: cancels under bn_o mean subtraction
  const float* emb       = (const float*)d_in[13];

  float* ws   = (float*)d_ws;
  uint4* wb   = (uint4*)d_ws;
  float* bufA = ws + BUFA_OFF;
  float* bufB = ws + BUFB_OFF;
  float* bufC = ws + BUFC_OFF;
  float* flat = ws + FLAT_OFF;
  float* fco  = ws + FCO_OFF;
  float* stats= ws + STATS_OFF;
  float* out  = (float*)d_out;

  hipMemsetAsync(fco, 0, (65536 + 3328) * sizeof(float), stream);

  prep_wb<<<1044, 256, 0, stream>>>(conv_w, convs_w, rb_c1_w, rb_c2_w,
                                    conv_out_w, wb);
  stem_mfma<<<512, 256, 0, stream>>>(s0, s1, wb, bufA);

  for (int i = 0; i < 6; ++i) {
    float* st1 = stats + (size_t)(2 * i) * 256;
    float* st2 = stats + (size_t)(2 * i + 1) * 256;
    const uint4* wb1 = wb + (size_t)(1728 + i * 864) * 64;
    const uint4* wb2 = wb + (size_t)(1728 + (6 + i) * 864) * 64;
    if (i == 0) {
      conv_mfma<0, 8, 1, 0><<<512, 256, 0, stream>>>(
          bufA, nullptr, nullptr, wb1, nullptr, nullptr, nullptr, bufB, st1);
    } else {
      conv_mfma<2, 8, 1, 0><<<512, 256, 0, stream>>>(
          bufC, bufA, bufA, wb1, stats + (size_t)(2 * i - 1) * 256,
          rb_bn2_s + (size_t)(i - 1) * 128, rb_bn2_b + (size_t)(i - 1) * 128,
          bufB, st1);
    }
    conv_mfma<1, 8, 1, 0><<<512, 256, 0, stream>>>(
        bufB, nullptr, nullptr, wb2, st1,
        rb_bn1_s + (size_t)i * 128, rb_bn1_b + (size_t)i * 128, bufC, st2);
  }

  conv_mfma<2, 4, 0, 1><<<512, 256, 0, stream>>>(
      bufC, bufA, bufA, wb + (size_t)12096 * 64, stats + 11u * 256,
      rb_bn2_s + 5u * 128, rb_bn2_b + 5u * 128, flat, nullptr);

  fc_kernel<<<dim3(16, 6), 256, 0, stream>>>(flat, fc_w, fco);
  fcstats_kernel<<<128, 64, 0, stream>>>(fco, stats + 12u * 256);
  vq_kernel<<<512, 256, 0, stream>>>(fco, stats + 12u * 256, emb, out);
  perp_kernel<<<1, 512, 0, stream>>>(out);
}

// Round 8
// 782.714 us; speedup vs baseline: 2.5349x; 1.0328x over previous
//
#include <hip/hip_runtime.h>
#include <cstdint>
#include <cstddef>

// ---------------------------------------------------------------------------
// LatentActionGen forward on MI355X — round 8: byte-identical resubmit of
// round-7 LDS diet (GPU never acquired in round 7).
//   conv planes 88->64 rows (guard rows removed; dummy M-rows read a valid
//   interior row and are excluded from stats) -> ~50 KB -> 3 blocks/CU.
//   stem restructured as two sequential K=1152 passes over one 3-plane
//   buffer (s0 then s1) -> 48 KB (was 135 KB) -> 1 -> 3 blocks/CU.
// Everything else (3-plane bf16 split, 6 MFMAs/product, fused BN/res/relu,
// prep_wb layout, fc/vq/perp tail) unchanged from the validated round-6 run.
// ---------------------------------------------------------------------------

typedef __attribute__((ext_vector_type(8))) short bf16x8;
typedef __attribute__((ext_vector_type(4))) float f32x4;

#define EPS_  1e-5f
#define NTOT_ 18432.0f

// ws float offsets
#define BUFA_OFF  3207168u   // wb = 12528 chunks * 1KB = 12528 KB
#define BUFB_OFF  5566464u
#define BUFC_OFF  7925760u
#define FLAT_OFF  BUFB_OFF   // flat aliases bufB (dead by conv_out)
#define FCO_OFF   10285056u
#define STATS_OFF 10350592u

// d_out offsets (floats)
#define LOSS_OFF 2359296u
#define PERP_OFF 2359808u
#define IDX_OFF  2359809u

__device__ __forceinline__ unsigned short f2bf(float v) {
  unsigned u = __float_as_uint(v);
  return (unsigned short)((u + 0x7fffu + ((u >> 16) & 1u)) >> 16);
}
__device__ __forceinline__ float bf2f(unsigned short h) {
  return __uint_as_float((unsigned)h << 16);
}
// swizzled 16B-slot index within a 64-row plane (injective: XOR on low-3
// bits of the cio field only)
__device__ __forceinline__ int swz16(int pr, int cio) {
  return (pr * 16 + cio) ^ ((pr ^ (pr >> 3)) & 7);
}

#define MF(Aa, Bb, Cc) Cc = __builtin_amdgcn_mfma_f32_16x16x32_bf16(Aa, Bb, Cc, 0, 0, 0)

// ---------------------------------------------------------------------------
// Weight prep: B-frag chunks (unchanged layout).
//   stem:  (nt*72 + ks)*3 + p               [ks<36: conv_w, else convs_w]
//   tower: 1728 + ((L*8+nt)*36 + ks)*3 + p  [L<6: c1[L], else c2[L-6]]
//   cout:  12096 + (nt*36 + ks)*3 + p
// ---------------------------------------------------------------------------
__global__ __launch_bounds__(256) void prep_wb(
    const float* __restrict__ conv_w, const float* __restrict__ convs_w,
    const float* __restrict__ c1w, const float* __restrict__ c2w,
    const float* __restrict__ cow, uint4* __restrict__ wb) {
  const int ct = blockIdx.x * 4 + (threadIdx.x >> 6);
  const int lane = threadIdx.x & 63;
  const float* src;
  int n, ks_eff, chbase;
  if (ct < 576) {
    int ks = ct % 72;
    src = (ks < 36) ? conv_w : convs_w;
    ks_eff = (ks < 36) ? ks : ks - 36;
    n = (ct / 72) * 16 + (lane & 15);
    chbase = ct * 3;
  } else if (ct < 4032) {
    int q = ct - 576;
    int L = q / 288, r = q % 288;
    src = (L < 6) ? (c1w + (size_t)L * 147456u) : (c2w + (size_t)(L - 6) * 147456u);
    ks_eff = r % 36;
    n = (r / 36) * 16 + (lane & 15);
    chbase = 1728 + q * 3;
  } else {
    int q = ct - 4032;
    src = cow;
    ks_eff = q % 36;
    n = (q / 36) * 16 + (lane & 15);
    chbase = 12096 + q * 3;
  }
  const int tap = ks_eff >> 2;
  const int ci0 = (ks_eff & 3) * 32 + (lane >> 4) * 8;
  uint4 q1, q2, q3;
  unsigned* u1 = (unsigned*)&q1;
  unsigned* u2 = (unsigned*)&q2;
  unsigned* u3 = (unsigned*)&q3;
#pragma unroll
  for (int j = 0; j < 4; ++j) {
    float va = src[((size_t)n * 128 + ci0 + 2 * j) * 9 + tap];
    float vb = src[((size_t)n * 128 + ci0 + 2 * j + 1) * 9 + tap];
    unsigned short a1 = f2bf(va), b1 = f2bf(vb);
    float ra = va - bf2f(a1), rb = vb - bf2f(b1);
    unsigned short a2 = f2bf(ra), b2 = f2bf(rb);
    ra -= bf2f(a2); rb -= bf2f(b2);
    u1[j] = (unsigned)a1 | ((unsigned)b1 << 16);
    u2[j] = (unsigned)a2 | ((unsigned)b2 << 16);
    u3[j] = (unsigned)f2bf(ra) | ((unsigned)f2bf(rb) << 16);
  }
  wb[(size_t)(chbase + 0) * 64 + lane] = q1;
  wb[(size_t)(chbase + 1) * 64 + lane] = q2;
  wb[(size_t)(chbase + 2) * 64 + lane] = q3;
}

// ---------------------------------------------------------------------------
// MFMA conv layer. Block = 1 image. LDS: 3 planes x 64 rows x 128 ci bf16
// = 48 KB -> 3 blocks/CU. Dummy M-rows (px>=36) read interior row 9
// (garbage) and are excluded from stats/stores.
// ---------------------------------------------------------------------------
template <int MODE, int NTILES, int STATS, int OUTFLAT>
__global__ __launch_bounds__(256) void conv_mfma(
    const float* __restrict__ in, const float* __restrict__ idn,
    float* __restrict__ xback, const uint4* __restrict__ wbL,
    const float* __restrict__ stats_in, const float* __restrict__ gamma,
    const float* __restrict__ beta, float* __restrict__ out,
    float* __restrict__ stats_out) {
  constexpr int NTPW = NTILES / 4;
  __shared__ __align__(16) unsigned short apl[3 * 8192];
  __shared__ __align__(16) float As[128], Bs[128];
  const int t = threadIdx.x, b = blockIdx.x;

  if (MODE >= 1 && t < 128) {
    float m = stats_in[t] * (1.0f / NTOT_);
    float var = stats_in[128 + t] * (1.0f / NTOT_) - m * m;
    float A = rsqrtf(var + EPS_) * gamma[t];
    As[t] = A;
    Bs[t] = fmaf(-m, A, beta[t]);
  }
  uint4* z4 = (uint4*)apl;
  for (int i = t; i < 3072; i += 256) z4[i] = make_uint4(0, 0, 0, 0);
  __syncthreads();

  const float4* in4 = (const float4*)in;
  const float4* idn4 = (const float4*)idn;
  float4* xb4 = (float4*)xback;
  const float4* As4 = (const float4*)As;
  const float4* Bs4 = (const float4*)Bs;
  for (int e = t; e < 576; e += 256) {
    int px = e >> 4, cich = e & 15;
    size_t gi = (size_t)(b * 36 + px) * 32 + cich * 2;
    float4 v0 = in4[gi], v1 = in4[gi + 1];
    if (MODE >= 1) {
      float4 A0 = As4[cich * 2], B0 = Bs4[cich * 2];
      float4 A1 = As4[cich * 2 + 1], B1 = Bs4[cich * 2 + 1];
      v0.x = fmaf(v0.x, A0.x, B0.x); v0.y = fmaf(v0.y, A0.y, B0.y);
      v0.z = fmaf(v0.z, A0.z, B0.z); v0.w = fmaf(v0.w, A0.w, B0.w);
      v1.x = fmaf(v1.x, A1.x, B1.x); v1.y = fmaf(v1.y, A1.y, B1.y);
      v1.z = fmaf(v1.z, A1.z, B1.z); v1.w = fmaf(v1.w, A1.w, B1.w);
      if (MODE == 2) {
        float4 d0 = idn4[gi], d1 = idn4[gi + 1];
        v0.x += d0.x; v0.y += d0.y; v0.z += d0.z; v0.w += d0.w;
        v1.x += d1.x; v1.y += d1.y; v1.z += d1.z; v1.w += d1.w;
      }
      v0.x = fmaxf(v0.x, 0.f); v0.y = fmaxf(v0.y, 0.f);
      v0.z = fmaxf(v0.z, 0.f); v0.w = fmaxf(v0.w, 0.f);
      v1.x = fmaxf(v1.x, 0.f); v1.y = fmaxf(v1.y, 0.f);
      v1.z = fmaxf(v1.z, 0.f); v1.w = fmaxf(v1.w, 0.f);
      if (MODE == 2) { xb4[gi] = v0; xb4[gi + 1] = v1; }
    }
    float vv[8] = {v0.x, v0.y, v0.z, v0.w, v1.x, v1.y, v1.z, v1.w};
    uint4 q1, q2, q3;
    unsigned* u1 = (unsigned*)&q1;
    unsigned* u2 = (unsigned*)&q2;
    unsigned* u3 = (unsigned*)&q3;
#pragma unroll
    for (int j = 0; j < 4; ++j) {
      unsigned short a1 = f2bf(vv[2 * j]), b1 = f2bf(vv[2 * j + 1]);
      float ra = vv[2 * j] - bf2f(a1), rb = vv[2 * j + 1] - bf2f(b1);
      unsigned short a2 = f2bf(ra), b2 = f2bf(rb);
      ra -= bf2f(a2); rb -= bf2f(b2);
      u1[j] = (unsigned)a1 | ((unsigned)b1 << 16);
      u2[j] = (unsigned)a2 | ((unsigned)b2 << 16);
      u3[j] = (unsigned)f2bf(ra) | ((unsigned)f2bf(rb) << 16);
    }
    int hh = px / 6, ww = px - hh * 6;
    int pp = (hh + 1) * 8 + (ww + 1);
    int a16 = swz16(pp, cich);
    z4[0 * 1024 + a16] = q1;
    z4[1 * 1024 + a16] = q2;
    z4[2 * 1024 + a16] = q3;
  }
  __syncthreads();

  const int wave = t >> 6, lane = t & 63;
  const int l15 = lane & 15, kq = lane >> 4;
  int ppb[3];
#pragma unroll
  for (int mt = 0; mt < 3; ++mt) {
    int px = mt * 16 + l15;
    ppb[mt] = (px < 36) ? ((px / 6 + 1) * 8 + (px % 6) + 1) : 9;
  }
  f32x4 zz = {0.f, 0.f, 0.f, 0.f};
  f32x4 acc[3][NTPW];
#pragma unroll
  for (int mt = 0; mt < 3; ++mt)
#pragma unroll
    for (int n2 = 0; n2 < NTPW; ++n2) acc[mt][n2] = zz;

  for (int tap = 0; tap < 9; ++tap) {
    const int dyx = (tap / 3 - 1) * 8 + (tap % 3) - 1;
#pragma unroll
    for (int kc = 0; kc < 4; ++kc) {
      const int ks = tap * 4 + kc;
      bf16x8 bfr[NTPW][3];
#pragma unroll
      for (int n2 = 0; n2 < NTPW; ++n2)
#pragma unroll
        for (int pl = 0; pl < 3; ++pl)
          bfr[n2][pl] = __builtin_bit_cast(bf16x8,
              wbL[((size_t)((wave * NTPW + n2) * 36 + ks) * 3 + pl) * 64 + lane]);
      bf16x8 afr[3][3];
#pragma unroll
      for (int mt = 0; mt < 3; ++mt) {
        int pr = ppb[mt] + dyx;
        int a16 = swz16(pr, kc * 4 + kq);
#pragma unroll
        for (int pl = 0; pl < 3; ++pl)
          afr[mt][pl] = *(const bf16x8*)(apl + pl * 8192 + a16 * 8);
      }
#pragma unroll
      for (int mt = 0; mt < 3; ++mt)
#pragma unroll
        for (int n2 = 0; n2 < NTPW; ++n2) {
          MF(afr[mt][0], bfr[n2][0], acc[mt][n2]);
          MF(afr[mt][1], bfr[n2][0], acc[mt][n2]);
          MF(afr[mt][0], bfr[n2][1], acc[mt][n2]);
          MF(afr[mt][2], bfr[n2][0], acc[mt][n2]);
          MF(afr[mt][1], bfr[n2][1], acc[mt][n2]);
          MF(afr[mt][0], bfr[n2][2], acc[mt][n2]);
        }
    }
  }

  float s[NTPW], sq[NTPW];
#pragma unroll
  for (int n2 = 0; n2 < NTPW; ++n2) { s[n2] = 0.f; sq[n2] = 0.f; }
#pragma unroll
  for (int mt = 0; mt < 3; ++mt)
#pragma unroll
    for (int n2 = 0; n2 < NTPW; ++n2) {
      const int cc = (wave * NTPW + n2) * 16 + l15;
#pragma unroll
      for (int q = 0; q < 4; ++q) {
        int px = mt * 16 + kq * 4 + q;
        float v = acc[mt][n2][q];
        if (px < 36) {
          if (OUTFLAT) out[(size_t)b * 2304 + cc * 36 + px] = v;
          else out[((size_t)b * 36 + px) * 128 + cc] = v;
          s[n2] += v; sq[n2] = fmaf(v, v, sq[n2]);
        }
      }
    }
  if (STATS) {
#pragma unroll
    for (int n2 = 0; n2 < NTPW; ++n2) {
      float sv = s[n2], qv = sq[n2];
      sv += __shfl_xor(sv, 16); qv += __shfl_xor(qv, 16);
      sv += __shfl_xor(sv, 32); qv += __shfl_xor(qv, 32);
      if (kq == 0) {
        const int cc = (wave * NTPW + n2) * 16 + l15;
        atomicAdd(&stats_out[cc], sv);
        atomicAdd(&stats_out[128 + cc], qv);
      }
    }
  }
}

// ---------------------------------------------------------------------------
// Stem: relu(conv(s0,w0)+conv(s1,w1)). Two sequential K=1152 passes over ONE
// 3-plane 48 KB buffer (acc carried in registers) -> 3 blocks/CU.
// ---------------------------------------------------------------------------
__global__ __launch_bounds__(256) void stem_mfma(
    const float* __restrict__ s0, const float* __restrict__ s1,
    const uint4* __restrict__ wbL, float* __restrict__ out) {
  __shared__ __align__(16) unsigned short apl[3 * 8192];
  const int t = threadIdx.x, b = blockIdx.x;
  uint4* z4 = (uint4*)apl;
  for (int i = t; i < 3072; i += 256) z4[i] = make_uint4(0, 0, 0, 0);

  const int wave = t >> 6, lane = t & 63;
  const int l15 = lane & 15, kq = lane >> 4;
  int ppb[3];
#pragma unroll
  for (int mt = 0; mt < 3; ++mt) {
    int px = mt * 16 + l15;
    ppb[mt] = (px < 36) ? ((px / 6 + 1) * 8 + (px % 6) + 1) : 9;
  }
  f32x4 zz = {0.f, 0.f, 0.f, 0.f};
  f32x4 acc[3][2];
#pragma unroll
  for (int mt = 0; mt < 3; ++mt) { acc[mt][0] = zz; acc[mt][1] = zz; }

  for (int pass = 0; pass < 2; ++pass) {
    __syncthreads();  // pass0: zero-init done; pass1: all reads of pass0 done
    const float* sp = pass ? s1 : s0;
    for (int e = t; e < 4608; e += 256) {
      int c = e / 36, px = e - c * 36;
      int hh = px / 6, ww = px - hh * 6;
      int pp = (hh + 1) * 8 + (ww + 1);
      int sw = swz16(pp, c >> 3) * 8 + (c & 7);
      float v0 = sp[(size_t)b * 4608 + e];
      unsigned short h; float r;
      h = f2bf(v0); apl[0 * 8192 + sw] = h; r = v0 - bf2f(h);
      h = f2bf(r);  apl[1 * 8192 + sw] = h; r -= bf2f(h);
      apl[2 * 8192 + sw] = f2bf(r);
    }
    __syncthreads();

    for (int tap = 0; tap < 9; ++tap) {
      const int dyx = (tap / 3 - 1) * 8 + (tap % 3) - 1;
#pragma unroll
      for (int kc = 0; kc < 4; ++kc) {
        const int ks = pass * 36 + tap * 4 + kc;
        bf16x8 bfr[2][3];
#pragma unroll
        for (int n2 = 0; n2 < 2; ++n2)
#pragma unroll
          for (int pl = 0; pl < 3; ++pl)
            bfr[n2][pl] = __builtin_bit_cast(bf16x8,
                wbL[((size_t)((wave * 2 + n2) * 72 + ks) * 3 + pl) * 64 + lane]);
        bf16x8 afr[3][3];
#pragma unroll
        for (int mt = 0; mt < 3; ++mt) {
          int pr = ppb[mt] + dyx;
          int a16 = swz16(pr, kc * 4 + kq);
#pragma unroll
          for (int pl = 0; pl < 3; ++pl)
            afr[mt][pl] = *(const bf16x8*)(apl + pl * 8192 + a16 * 8);
        }
#pragma unroll
        for (int mt = 0; mt < 3; ++mt)
#pragma unroll
          for (int n2 = 0; n2 < 2; ++n2) {
            MF(afr[mt][0], bfr[n2][0], acc[mt][n2]);
            MF(afr[mt][1], bfr[n2][0], acc[mt][n2]);
            MF(afr[mt][0], bfr[n2][1], acc[mt][n2]);
            MF(afr[mt][2], bfr[n2][0], acc[mt][n2]);
            MF(afr[mt][1], bfr[n2][1], acc[mt][n2]);
            MF(afr[mt][0], bfr[n2][2], acc[mt][n2]);
          }
      }
    }
  }
#pragma unroll
  for (int mt = 0; mt < 3; ++mt)
#pragma unroll
    for (int n2 = 0; n2 < 2; ++n2) {
      const int cc = (wave * 2 + n2) * 16 + l15;
#pragma unroll
      for (int q = 0; q < 4; ++q) {
        int px = mt * 16 + kq * 4 + q;
        if (px < 36)
          out[((size_t)b * 36 + px) * 128 + cc] = fmaxf(acc[mt][n2][q], 0.f);
      }
    }
}

// ---------------------------------------------------------------------------
// FC / stats / VQ / perplexity (unchanged, silicon-validated)
// ---------------------------------------------------------------------------
__global__ __launch_bounds__(256) void fc_kernel(
    const float* __restrict__ flat, const float* __restrict__ fcw,
    float* __restrict__ out) {
  __shared__ __align__(16) float fs[32 * 384];
  const int t = threadIdx.x;
  const int b0 = blockIdx.x * 32;
  const int k04 = blockIdx.y * 96;
  float4* fs4 = (float4*)fs;
  const float4* fl4 = (const float4*)flat;
  for (int i = t; i < 3072; i += 256) {
    int r = i / 96, k = i - r * 96;
    fs4[i] = fl4[(size_t)(b0 + r) * 576 + k04 + k];
  }
  __syncthreads();
  const int tc = t & 31, tp = t >> 5;
  const float4* fw4 = (const float4*)fcw;
  float acc[4][4];
#pragma unroll
  for (int r = 0; r < 4; ++r)
#pragma unroll
    for (int j = 0; j < 4; ++j) acc[r][j] = 0.f;
  for (int k = 0; k < 96; ++k) {
    float4 w[4];
#pragma unroll
    for (int j = 0; j < 4; ++j) w[j] = fw4[(size_t)(tc + 32 * j) * 576 + k04 + k];
    float4 x[4];
#pragma unroll
    for (int r = 0; r < 4; ++r) x[r] = fs4[(tp * 4 + r) * 96 + k];
#pragma unroll
    for (int r = 0; r < 4; ++r)
#pragma unroll
      for (int j = 0; j < 4; ++j) {
        acc[r][j] = fmaf(x[r].x, w[j].x, acc[r][j]);
        acc[r][j] = fmaf(x[r].y, w[j].y, acc[r][j]);
        acc[r][j] = fmaf(x[r].z, w[j].z, acc[r][j]);
        acc[r][j] = fmaf(x[r].w, w[j].w, acc[r][j]);
      }
  }
#pragma unroll
  for (int r = 0; r < 4; ++r)
#pragma unroll
    for (int j = 0; j < 4; ++j)
      atomicAdd(&out[(size_t)(b0 + tp * 4 + r) * 128 + tc + 32 * j], acc[r][j]);
}

__global__ __launch_bounds__(64) void fcstats_kernel(const float* __restrict__ fco,
                                                     float* __restrict__ st) {
  const int e = blockIdx.x, l = threadIdx.x;
  float s = 0.f, q = 0.f;
  for (int b = l; b < 512; b += 64) {
    float v = fco[(size_t)b * 128 + e];
    s += v; q = fmaf(v, v, q);
  }
  for (int off = 32; off; off >>= 1) {
    s += __shfl_down(s, off);
    q += __shfl_down(q, off);
  }
  if (l == 0) { st[e] = s; st[128 + e] = q; }
}

__global__ __launch_bounds__(256) void vq_kernel(
    const float* __restrict__ fco, const float* __restrict__ st,
    const float* __restrict__ emb, float* __restrict__ dout) {
  __shared__ __align__(16) float fn[128], qv[128];
  __shared__ unsigned long long wmin[4];
  __shared__ float lred[2];
  const int t = threadIdx.x, b = blockIdx.x;
  if (t < 128) {
    float m = st[t] * (1.0f / 512.0f);
    float var = st[128 + t] * (1.0f / 512.0f) - m * m;
    float rs = rsqrtf(var + EPS_);
    fn[t] = (fco[(size_t)b * 128 + t] - m) * rs;
  }
  __syncthreads();
  const float4* e4 = (const float4*)emb;
  const float4* f4 = (const float4*)fn;
  unsigned long long best = ~0ull;
  for (int k = t; k < 512; k += 256) {
    float d = 0.f;
#pragma unroll 4
    for (int j = 0; j < 32; ++j) {
      float4 e = e4[(size_t)k * 32 + j];
      float4 f = f4[j];
      float dx = f.x - e.x, dy = f.y - e.y, dz = f.z - e.z, dw = f.w - e.w;
      d = fmaf(dx, dx, d); d = fmaf(dy, dy, d);
      d = fmaf(dz, dz, d); d = fmaf(dw, dw, d);
    }
    unsigned long long key = ((unsigned long long)__float_as_uint(d) << 32) | (unsigned)k;
    if (key < best) best = key;
  }
  for (int off = 32; off; off >>= 1) {
    unsigned long long o = __shfl_down(best, off);
    if (o < best) best = o;
  }
  if ((t & 63) == 0) wmin[t >> 6] = best;
  __syncthreads();
  if (t == 0) {
    unsigned long long m01 = wmin[0] < wmin[1] ? wmin[0] : wmin[1];
    unsigned long long m23 = wmin[2] < wmin[3] ? wmin[2] : wmin[3];
    wmin[0] = m01 < m23 ? m01 : m23;
  }
  __syncthreads();
  const int ks = (int)(wmin[0] & 0xffffffffu);
  if (t < 128) qv[t] = emb[(size_t)ks * 128 + t];
  __syncthreads();
  if (t < 128) {
    float df = qv[t] - fn[t];
    float sq = df * df;
    for (int off = 32; off; off >>= 1) sq += __shfl_down(sq, off);
    if ((t & 63) == 0) lred[t >> 6] = sq;
  }
  __syncthreads();
  if (t == 0) dout[LOSS_OFF + b] = (lred[0] + lred[1]) * (2.0f / 128.0f);
  float4* z4 = (float4*)dout;
  for (int i = t; i < 1152; i += 256) {
    int e = i / 9, j = i - e * 9;
    float v = qv[e];
    z4[((size_t)b * 128 + e) * 9 + j] = make_float4(v, v, v, v);
  }
  if (t == 0) dout[IDX_OFF + b] = (float)ks;
}

__global__ __launch_bounds__(512) void perp_kernel(float* __restrict__ dout) {
  __shared__ int hist[512];
  __shared__ float wr[8];
  const int t = threadIdx.x;
  hist[t] = 0;
  __syncthreads();
  int k = (int)dout[IDX_OFF + t];
  atomicAdd(&hist[k], 1);
  __syncthreads();
  float p = hist[t] * (1.0f / 512.0f);
  float term = p * logf(p + 1e-10f);
  for (int off = 32; off; off >>= 1) term += __shfl_down(term, off);
  if ((t & 63) == 0) wr[t >> 6] = term;
  __syncthreads();
  if (t == 0) {
    float s = 0.f;
#pragma unroll
    for (int i = 0; i < 8; ++i) s += wr[i];
    dout[PERP_OFF] = expf(-s);
  }
}

// ---------------------------------------------------------------------------
extern "C" void kernel_launch(void* const* d_in, const int* in_sizes, int n_in,
                              void* d_out, int out_size, void* d_ws, size_t ws_size,
                              hipStream_t stream) {
  const float* s0        = (const float*)d_in[0];
  const float* s1        = (const float*)d_in[1];
  const float* conv_w    = (const float*)d_in[2];
  const float* convs_w   = (const float*)d_in[3];
  const float* rb_c1_w   = (const float*)d_in[4];
  const float* rb_bn1_s  = (const float*)d_in[5];
  const float* rb_bn1_b  = (const float*)d_in[6];
  const float* rb_c2_w   = (const float*)d_in[7];
  const float* rb_bn2_s  = (const float*)d_in[8];
  const float* rb_bn2_b  = (const float*)d_in[9];
  const float* conv_out_w= (const float*)d_in[10];
  const float* fc_w      = (const float*)d_in[11];
  // d_in[12] = fc_b: cancels under bn_o mean subtraction
  const float* emb       = (const float*)d_in[13];

  float* ws   = (float*)d_ws;
  uint4* wb   = (uint4*)d_ws;
  float* bufA = ws + BUFA_OFF;
  float* bufB = ws + BUFB_OFF;
  float* bufC = ws + BUFC_OFF;
  float* flat = ws + FLAT_OFF;
  float* fco  = ws + FCO_OFF;
  float* stats= ws + STATS_OFF;
  float* out  = (float*)d_out;

  hipMemsetAsync(fco, 0, (65536 + 3328) * sizeof(float), stream);

  prep_wb<<<1044, 256, 0, stream>>>(conv_w, convs_w, rb_c1_w, rb_c2_w,
                                    conv_out_w, wb);
  stem_mfma<<<512, 256, 0, stream>>>(s0, s1, wb, bufA);

  for (int i = 0; i < 6; ++i) {
    float* st1 = stats + (size_t)(2 * i) * 256;
    float* st2 = stats + (size_t)(2 * i + 1) * 256;
    const uint4* wb1 = wb + (size_t)(1728 + i * 864) * 64;
    const uint4* wb2 = wb + (size_t)(1728 + (6 + i) * 864) * 64;
    if (i == 0) {
      conv_mfma<0, 8, 1, 0><<<512, 256, 0, stream>>>(
          bufA, nullptr, nullptr, wb1, nullptr, nullptr, nullptr, bufB, st1);
    } else {
      conv_mfma<2, 8, 1, 0><<<512, 256, 0, stream>>>(
          bufC, bufA, bufA, wb1, stats + (size_t)(2 * i - 1) * 256,
          rb_bn2_s + (size_t)(i - 1) * 128, rb_bn2_b + (size_t)(i - 1) * 128,
          bufB, st1);
    }
    conv_mfma<1, 8, 1, 0><<<512, 256, 0, stream>>>(
        bufB, nullptr, nullptr, wb2, st1,
        rb_bn1_s + (size_t)i * 128, rb_bn1_b + (size_t)i * 128, bufC, st2);
  }

  conv_mfma<2, 4, 0, 1><<<512, 256, 0, stream>>>(
      bufC, bufA, bufA, wb + (size_t)12096 * 64, stats + 11u * 256,
      rb_bn2_s + 5u * 128, rb_bn2_b + 5u * 128, flat, nullptr);

  fc_kernel<<<dim3(16, 6), 256, 0, stream>>>(flat, fc_w, fco);
  fcstats_kernel<<<128, 64, 0, stream>>>(fco, stats + 12u * 256);
  vq_kernel<<<512, 256, 0, stream>>>(fco, stats + 12u * 256, emb, out);
  perp_kernel<<<1, 512, 0, stream>>>(out);
}